// Round 6
// baseline (42.073 us; speedup 1.0000x reference)
//
#include <hip/hip_runtime.h>

// B=4, LQ=256, LK=512, DQ=DK=DV=256, H=128
#define B_   4
#define LQ_  256
#define LK_  512
#define DQK_ 256
#define DV_  256
#define H_   128

#define TANH_C 2.8853900817779268f   // 2*log2(e): tanh(x) = 1 - 2/(exp2(TANH_C*x)+1)
#define L2E    1.4426950408889634f
#define NQBLK (B_ * LQ_ / 8)         // 128 q-proj blocks (TILE=8)
#define NKBLK (B_ * LK_ / 8)         // 256 k-proj blocks

// ---------------------------------------------------------------------------
// proj_kernel: fused q+k projection. TILE=8 rows/block, 128 threads (t = h).
// Rows staged in LDS (broadcast reads); W reads coalesced over t.
//   q blocks -> eq  [B*LQ, H]  = exp2(TANH_C * q@Wq)
//   k blocks -> ekT [B, H, LK] = exp2(TANH_C * k@Wk)   (transposed)
// ---------------------------------------------------------------------------
__global__ __launch_bounds__(128) void proj_kernel(const float* __restrict__ Q,
                                                   const float* __restrict__ K,
                                                   const float* __restrict__ Wq,
                                                   const float* __restrict__ Wk,
                                                   float* __restrict__ eq,
                                                   float* __restrict__ ekT) {
    __shared__ float rows[8 * DQK_];           // 8 KB
    const int blk = blockIdx.x;
    const bool isq = blk < NQBLK;
    const float* in = isq ? Q  : K;
    const float* W  = isq ? Wq : Wk;
    const int r0 = (isq ? blk : blk - NQBLK) * 8;
    const int t  = threadIdx.x;

    const float4* in4 = reinterpret_cast<const float4*>(in + (size_t)r0 * DQK_);
    float4* r4 = reinterpret_cast<float4*>(rows);
#pragma unroll
    for (int i = 0; i < 4; ++i) r4[t + 128 * i] = in4[t + 128 * i];
    __syncthreads();

    float acc[8];
#pragma unroll
    for (int j = 0; j < 8; ++j) acc[j] = 0.f;

#pragma unroll 2
    for (int d4 = 0; d4 < DQK_ / 4; ++d4) {
        float w0 = W[(size_t)(4 * d4 + 0) * H_ + t];   // coalesced
        float w1 = W[(size_t)(4 * d4 + 1) * H_ + t];
        float w2 = W[(size_t)(4 * d4 + 2) * H_ + t];
        float w3 = W[(size_t)(4 * d4 + 3) * H_ + t];
#pragma unroll
        for (int j = 0; j < 8; ++j) {
            float4 r = *reinterpret_cast<const float4*>(&rows[j * DQK_ + 4 * d4]); // LDS broadcast
            acc[j] = fmaf(r.x, w0, fmaf(r.y, w1, fmaf(r.z, w2, fmaf(r.w, w3, acc[j]))));
        }
    }
    float e[8];
#pragma unroll
    for (int j = 0; j < 8; ++j) e[j] = __builtin_amdgcn_exp2f(acc[j] * TANH_C);

    if (isq) {
#pragma unroll
        for (int j = 0; j < 8; ++j)
            eq[(size_t)(r0 + j) * H_ + t] = e[j];
    } else {
        const int b  = r0 >> 9;
        const int k0 = r0 & (LK_ - 1);
        float* o = ekT + ((size_t)(b * H_ + t)) * LK_ + k0;
        *reinterpret_cast<float4*>(o)     = make_float4(e[0], e[1], e[2], e[3]);
        *reinterpret_cast<float4*>(o + 4) = make_float4(e[4], e[5], e[6], e[7]);
    }
}

// ---------------------------------------------------------------------------
// attn_kernel: 512 blocks x 512 threads (8 waves; VGPR capped for 4 blk/CU).
//   block -> b = blk & 3 (co-resident blocks mix batches -> load balance),
//            qt = blk >> 2 (2 q-rows per block).
//  Stage: Eq rows (2x128) + wm2 = -2*wv in LDS.
//  Phase B: thread owns k = t; both q-rows share each ek load:
//           p += wm2[h] * rcp(fma(Eq[r][h], Ek[h][k], 1))  (1 trans/elem;
//           +sum(wv) const cancels in softmax). k >= valid -> -1e6.
//  Phase C: joint (row0,row1) masked softmax over 512 scores.
//  Phase D: thread (half = t>>8, v = t&255): both rows over k-half range
//           (clamped to valid; sc == 0 beyond valid anyway), LDS reduce.
// ---------------------------------------------------------------------------
__global__ __launch_bounds__(512, 8) void attn_kernel(
    const float* __restrict__ eq,          // [B*LQ, H]
    const float* __restrict__ ekT,         // [B, H, LK]
    const float* __restrict__ wv,          // [H]
    const float* __restrict__ values,      // [B, LK, DV]
    const int*   __restrict__ valid_lens,  // [B]
    float* __restrict__ out) {             // [B*LQ, DV]
    __shared__ float eq_l[2][H_];          // 1 KB
    __shared__ float wm2[H_];              // 512 B
    __shared__ float sc[LK_][2];           // 4 KB
    __shared__ float part[2][2][DV_];      // 4 KB
    __shared__ float red2[8][2];
    __shared__ float redm[2];
    __shared__ float inv_s[2];

    const int blk = blockIdx.x;            // 0..511
    const int b   = blk & 3;
    const int qt  = blk >> 2;              // 0..127
    const int t   = threadIdx.x;           // 0..511
    const int valid = valid_lens[b];

    if (t < 256) {
        eq_l[t >> 7][t & 127] = eq[(size_t)(b * LQ_ + qt * 2 + (t >> 7)) * H_ + (t & 127)];
    } else if (t < 384) {
        wm2[t - 256] = -2.f * wv[t - 256];
    }
    __syncthreads();

    // ---- Phase B: scores for k = t, rows 0 and 1 ----
    float s0 = -1e6f, s1 = -1e6f;
    if (t < valid) {
        const float* ekp = ekT + (size_t)b * H_ * LK_ + t;
        const float4* w4  = reinterpret_cast<const float4*>(wm2);
        const float4* qa4 = reinterpret_cast<const float4*>(eq_l[0]);
        const float4* qb4 = reinterpret_cast<const float4*>(eq_l[1]);
        float p0 = 0.f, p1 = 0.f;
#pragma unroll 4
        for (int h4 = 0; h4 < H_ / 4; ++h4) {
            float4 w  = w4[h4];
            float4 qa = qa4[h4];
            float4 qb = qb4[h4];
#pragma unroll
            for (int e = 0; e < 4; ++e) {
                float ek = ekp[(size_t)(4 * h4 + e) * LK_];   // coalesced over k
                float fa = fmaf(reinterpret_cast<const float*>(&qa)[e], ek, 1.f);
                float fb = fmaf(reinterpret_cast<const float*>(&qb)[e], ek, 1.f);
                float ww = reinterpret_cast<const float*>(&w)[e];
                p0 = fmaf(ww, __builtin_amdgcn_rcpf(fa), p0);
                p1 = fmaf(ww, __builtin_amdgcn_rcpf(fb), p1);
            }
        }
        s0 = p0;                            // -2 folded into wm2
        s1 = p1;
    }

    // ---- Phase C: joint masked softmax for both rows ----
    {
        float m0 = s0, m1 = s1;
#pragma unroll
        for (int off = 32; off; off >>= 1) {
            m0 = fmaxf(m0, __shfl_down(m0, off, 64));
            m1 = fmaxf(m1, __shfl_down(m1, off, 64));
        }
        if ((t & 63) == 0) { red2[t >> 6][0] = m0; red2[t >> 6][1] = m1; }
    }
    __syncthreads();
    if (t < 2) {
        float m = red2[0][t];
#pragma unroll
        for (int i = 1; i < 8; ++i) m = fmaxf(m, red2[i][t]);
        redm[t] = m;
    }
    __syncthreads();
    {
        float e0 = __builtin_amdgcn_exp2f((s0 - redm[0]) * L2E);
        float e1 = __builtin_amdgcn_exp2f((s1 - redm[1]) * L2E);
        sc[t][0] = e0;                      // 0 for masked k (exp2 underflow)
        sc[t][1] = e1;
        float t0 = e0, t1 = e1;
#pragma unroll
        for (int off = 32; off; off >>= 1) {
            t0 += __shfl_down(t0, off, 64);
            t1 += __shfl_down(t1, off, 64);
        }
        if ((t & 63) == 0) { red2[t >> 6][0] = t0; red2[t >> 6][1] = t1; }
    }
    __syncthreads();
    if (t < 2) {
        float s = red2[0][t];
#pragma unroll
        for (int i = 1; i < 8; ++i) s += red2[i][t];
        inv_s[t] = 1.f / s;
    }
    __syncthreads();

    // ---- Phase D: out = attn @ values ----
    {
        const int v    = t & 255;
        const int half = t >> 8;
        const int kstart = half * 256;
        const int kend   = min(kstart + 256, valid);
        const float* vb = values + (size_t)b * LK_ * DV_ + v;
        float a0 = 0.f, a1 = 0.f;
#pragma unroll 4
        for (int k = kstart; k < kend; ++k) {
            float2 f  = *reinterpret_cast<const float2*>(&sc[k][0]);  // LDS broadcast
            float val = vb[(size_t)k * DV_];                          // coalesced over v
            a0 = fmaf(f.x, val, a0);
            a1 = fmaf(f.y, val, a1);
        }
        part[half][0][v] = a0;
        part[half][1][v] = a1;
    }
    __syncthreads();
    {
        const int v = t & 255;
        const int r = t >> 8;
        out[(size_t)(b * LQ_ + qt * 2 + r) * DV_ + v] =
            (part[0][r][v] + part[1][r][v]) * inv_s[r];
    }
}

extern "C" void kernel_launch(void* const* d_in, const int* in_sizes, int n_in,
                              void* d_out, int out_size, void* d_ws, size_t ws_size,
                              hipStream_t stream) {
    const float* queries    = (const float*)d_in[0];  // [B, LQ, DQ]
    const float* keys       = (const float*)d_in[1];  // [B, LK, DK]
    const float* values     = (const float*)d_in[2];  // [B, LK, DV]
    const float* Wq         = (const float*)d_in[3];  // [DQ, H]
    const float* Wk         = (const float*)d_in[4];  // [DK, H]
    const float* wv         = (const float*)d_in[5];  // [H]
    const int*   valid_lens = (const int*)d_in[6];    // [B]
    float* out = (float*)d_out;

    float* eq  = (float*)d_ws;                   // [B*LQ, H]   512 KB
    float* ekT = eq + (size_t)B_ * LQ_ * H_;     // [B, H, LK]  1 MB

    proj_kernel<<<NQBLK + NKBLK, 128, 0, stream>>>(queries, keys, Wq, Wk, eq, ekT);
    attn_kernel<<<2 * B_ * LQ_ / 4, 512, 0, stream>>>(eq, ekT, wv, values, valid_lens, out);
}

// Round 7
// 41.200 us; speedup vs baseline: 1.0212x; 1.0212x over previous
//
#include <hip/hip_runtime.h>

// B=4, LQ=256, LK=512, DQ=DK=DV=256, H=128
#define B_   4
#define LQ_  256
#define LK_  512
#define DQK_ 256
#define DV_  256
#define H_   128

#define TANH_C 2.8853900817779268f   // 2*log2(e): tanh(x) = 1 - 2/(exp2(TANH_C*x)+1)
#define L2E    1.4426950408889634f
#define NQBLK (B_ * LQ_ / 4)         // 256 q-proj blocks (TILE=4)
#define NKBLK (B_ * LK_ / 4)         // 512 k-proj blocks

// ---------------------------------------------------------------------------
// proj_kernel (round-4 exact): fused q+k projection. TILE=4, 128 threads (t=h).
//   q blocks -> eq  [B*LQ, H]  = exp2(TANH_C * q@Wq)
//   k blocks -> ekT [B, H, LK] = exp2(TANH_C * k@Wk)   (transposed)
// ---------------------------------------------------------------------------
__global__ __launch_bounds__(128) void proj_kernel(const float* __restrict__ Q,
                                                   const float* __restrict__ K,
                                                   const float* __restrict__ Wq,
                                                   const float* __restrict__ Wk,
                                                   float* __restrict__ eq,
                                                   float* __restrict__ ekT) {
    const int blk = blockIdx.x;
    const bool isq = blk < NQBLK;
    const float* in = isq ? Q  : K;
    const float* W  = isq ? Wq : Wk;
    const int r0 = (isq ? blk : blk - NQBLK) * 4;
    const int t  = threadIdx.x;

    float acc0 = 0.f, acc1 = 0.f, acc2 = 0.f, acc3 = 0.f;
    const float4* in4 = reinterpret_cast<const float4*>(in + (size_t)r0 * DQK_);
    for (int d4 = 0; d4 < DQK_ / 4; ++d4) {
        float4 r0v = in4[0 * (DQK_ / 4) + d4];   // uniform -> s_load
        float4 r1v = in4[1 * (DQK_ / 4) + d4];
        float4 r2v = in4[2 * (DQK_ / 4) + d4];
        float4 r3v = in4[3 * (DQK_ / 4) + d4];
#pragma unroll
        for (int e = 0; e < 4; ++e) {
            float w = W[(size_t)(4 * d4 + e) * H_ + t];   // coalesced
            acc0 = fmaf(reinterpret_cast<const float*>(&r0v)[e], w, acc0);
            acc1 = fmaf(reinterpret_cast<const float*>(&r1v)[e], w, acc1);
            acc2 = fmaf(reinterpret_cast<const float*>(&r2v)[e], w, acc2);
            acc3 = fmaf(reinterpret_cast<const float*>(&r3v)[e], w, acc3);
        }
    }
    float e0 = __builtin_amdgcn_exp2f(acc0 * TANH_C);
    float e1 = __builtin_amdgcn_exp2f(acc1 * TANH_C);
    float e2 = __builtin_amdgcn_exp2f(acc2 * TANH_C);
    float e3 = __builtin_amdgcn_exp2f(acc3 * TANH_C);
    if (isq) {
        eq[(size_t)(r0 + 0) * H_ + t] = e0;
        eq[(size_t)(r0 + 1) * H_ + t] = e1;
        eq[(size_t)(r0 + 2) * H_ + t] = e2;
        eq[(size_t)(r0 + 3) * H_ + t] = e3;
    } else {
        const int b  = r0 >> 9;
        const int k0 = r0 & (LK_ - 1);
        float* o = ekT + ((size_t)(b * H_ + t)) * LK_ + k0;
        *reinterpret_cast<float4*>(o) = make_float4(e0, e1, e2, e3);
    }
}

// ---------------------------------------------------------------------------
// score_kernel: 256 blocks (qt) x 1024 threads. PERFECT LOAD BALANCE: every
// block handles row qt of ALL FOUR batches -> per-block work = sum_b valid[b].
//   thread: bb = t>>8 (batch, wave-uniform), kq = t&255, chains k = {kq, kq+256}
//   score  = sum_h wm2[h] * rcp(fma(Eq[bb][h], Ek[bb][h][k], 1))  (1 trans/elem;
//            -2 folded into wm2, +sum(wv) const cancels in softmax)
//   per-batch wave-coherent predication keeps the valid-mask savings.
//   Then per-row softmax (4 rows, 4 waves each) and NORMALIZED weights ->
//   attw[b*LQ+qt][k] (coalesced stores).
// ---------------------------------------------------------------------------
__global__ __launch_bounds__(1024) void score_kernel(
    const float* __restrict__ eq,          // [B*LQ, H]
    const float* __restrict__ ekT,         // [B, H, LK]
    const float* __restrict__ wv,          // [H]
    const int*   __restrict__ valid_lens,  // [B]
    float* __restrict__ attw) {            // [B*LQ, LK] normalized
    __shared__ float eq_l[4][H_];          // 2 KB (row qt of each batch)
    __shared__ float wm2[H_];              // 512 B
    __shared__ float red[16];
    __shared__ float redm[4];
    __shared__ float inv_s[4];

    const int qt = blockIdx.x;             // 0..255
    const int t  = threadIdx.x;            // 0..1023

    if (t < 512) {
        eq_l[t >> 7][t & 127] = eq[((size_t)(t >> 7) * LQ_ + qt) * H_ + (t & 127)];
    } else if (t < 640) {
        wm2[t - 512] = -2.f * wv[t - 512];
    }
    __syncthreads();

    const int bb = __builtin_amdgcn_readfirstlane(t >> 8);  // 0..3
    const int kq = t & 255;
    const int valid = valid_lens[bb];

    float s0 = -1e6f, s1 = -1e6f;
    {
        const float4* w4 = reinterpret_cast<const float4*>(wm2);
        const float4* q4 = reinterpret_cast<const float4*>(eq_l[bb]);
        const float* ekp = ekT + (size_t)bb * H_ * LK_ + kq;
        if (kq < valid) {
            if (kq + 256 < valid) {        // dual chain: k and k+256 both live
                float p0 = 0.f, p1 = 0.f;
#pragma unroll 2
                for (int h4 = 0; h4 < H_ / 4; ++h4) {
                    float4 w = w4[h4];
                    float4 q = q4[h4];
#pragma unroll
                    for (int e = 0; e < 4; ++e) {
                        const float* base = ekp + (size_t)(4 * h4 + e) * LK_;
                        float ek0 = base[0];     // coalesced over kq
                        float ek1 = base[256];
                        float qq = reinterpret_cast<const float*>(&q)[e];
                        float ww = reinterpret_cast<const float*>(&w)[e];
                        p0 = fmaf(ww, __builtin_amdgcn_rcpf(fmaf(qq, ek0, 1.f)), p0);
                        p1 = fmaf(ww, __builtin_amdgcn_rcpf(fmaf(qq, ek1, 1.f)), p1);
                    }
                }
                s0 = p0; s1 = p1;
            } else {                       // single chain: only k = kq live
                float p0 = 0.f;
#pragma unroll 2
                for (int h4 = 0; h4 < H_ / 4; ++h4) {
                    float4 w = w4[h4];
                    float4 q = q4[h4];
#pragma unroll
                    for (int e = 0; e < 4; ++e) {
                        float ek0 = ekp[(size_t)(4 * h4 + e) * LK_];
                        float qq = reinterpret_cast<const float*>(&q)[e];
                        float ww = reinterpret_cast<const float*>(&w)[e];
                        p0 = fmaf(ww, __builtin_amdgcn_rcpf(fmaf(qq, ek0, 1.f)), p0);
                    }
                }
                s0 = p0;
            }
        }
    }

    // ---- per-row softmax: row r <- waves 4r..4r+3 (bb == w>>2) ----
    const int w = t >> 6;                  // wave id 0..15
    {
        float m = fmaxf(s0, s1);
#pragma unroll
        for (int off = 32; off; off >>= 1) m = fmaxf(m, __shfl_down(m, off, 64));
        if ((t & 63) == 0) red[w] = m;
    }
    __syncthreads();
    if (t < 4) {
        redm[t] = fmaxf(fmaxf(red[4 * t], red[4 * t + 1]),
                        fmaxf(red[4 * t + 2], red[4 * t + 3]));
    }
    __syncthreads();
    const float m = redm[bb];
    float e0 = __builtin_amdgcn_exp2f((s0 - m) * L2E);   // 0 for masked k
    float e1 = __builtin_amdgcn_exp2f((s1 - m) * L2E);
    {
        float ss = e0 + e1;
#pragma unroll
        for (int off = 32; off; off >>= 1) ss += __shfl_down(ss, off, 64);
        if ((t & 63) == 0) red[w] = ss;
    }
    __syncthreads();
    if (t < 4) {
        inv_s[t] = 1.f / (red[4 * t] + red[4 * t + 1] + red[4 * t + 2] + red[4 * t + 3]);
    }
    __syncthreads();
    {
        const float inv = inv_s[bb];
        float* ap = attw + ((size_t)(bb * LQ_ + qt)) * LK_ + kq;
        ap[0]   = e0 * inv;                // coalesced over kq
        ap[256] = e1 * inv;
    }
}

// ---------------------------------------------------------------------------
// pv_kernel (round-4 phase D as standalone): 256 blocks x 1024 threads.
//   b = blk>>6, qt = blk&63 (4 same-batch rows -> 4-way values amortization).
//   Stage attw rows transposed into sc[k][r]; thread (kh, v) accumulates
//   4 rows over its k-range (clamped to valid; attw==0 beyond), LDS reduce.
// ---------------------------------------------------------------------------
__global__ __launch_bounds__(1024) void pv_kernel(
    const float* __restrict__ attw,        // [B*LQ, LK] normalized
    const float* __restrict__ values,      // [B, LK, DV]
    const int*   __restrict__ valid_lens,  // [B]
    float* __restrict__ out) {             // [B*LQ, DV]
    __shared__ float sc[LK_][4];           // [k][r] 8 KB
    __shared__ float part[4][4][DV_];      // [kh][r][v] 16 KB

    const int blk = blockIdx.x;
    const int b   = blk >> 6;
    const int qt  = blk & 63;
    const int t   = threadIdx.x;
    const int valid = valid_lens[b];

    // stage 4 rows of attw -> sc[k][r]
#pragma unroll
    for (int i = 0; i < 2; ++i) {
        int idx = t + 1024 * i;
        int r = idx >> 9, k = idx & 511;
        sc[k][r] = attw[((size_t)(b * LQ_ + qt * 4 + r)) * LK_ + k];  // coalesced
    }
    __syncthreads();

    {
        const int kh = __builtin_amdgcn_readfirstlane(t >> 8);   // 0..3
        const int v  = t & 255;
        const int kstart = kh * 128;
        const int kend   = min(kstart + 128, valid);
        const float* vb = values + (size_t)b * LK_ * DV_ + v;
        float a0 = 0.f, a1 = 0.f, a2 = 0.f, a3 = 0.f;
#pragma unroll 4
        for (int k = kstart; k < kend; ++k) {
            float4 f  = *reinterpret_cast<const float4*>(&sc[k][0]);  // LDS broadcast
            float val = vb[(size_t)k * DV_];                          // coalesced over v
            a0 = fmaf(f.x, val, a0);
            a1 = fmaf(f.y, val, a1);
            a2 = fmaf(f.z, val, a2);
            a3 = fmaf(f.w, val, a3);
        }
        part[kh][0][v] = a0;
        part[kh][1][v] = a1;
        part[kh][2][v] = a2;
        part[kh][3][v] = a3;
    }
    __syncthreads();
    {
        const int qi = t >> 8;
        const int v  = t & 255;
        out[(size_t)(b * LQ_ + qt * 4 + qi) * DV_ + v] =
            (part[0][qi][v] + part[1][qi][v]) + (part[2][qi][v] + part[3][qi][v]);
    }
}

extern "C" void kernel_launch(void* const* d_in, const int* in_sizes, int n_in,
                              void* d_out, int out_size, void* d_ws, size_t ws_size,
                              hipStream_t stream) {
    const float* queries    = (const float*)d_in[0];  // [B, LQ, DQ]
    const float* keys       = (const float*)d_in[1];  // [B, LK, DK]
    const float* values     = (const float*)d_in[2];  // [B, LK, DV]
    const float* Wq         = (const float*)d_in[3];  // [DQ, H]
    const float* Wk         = (const float*)d_in[4];  // [DK, H]
    const float* wv         = (const float*)d_in[5];  // [H]
    const int*   valid_lens = (const int*)d_in[6];    // [B]
    float* out = (float*)d_out;

    float* eq   = (float*)d_ws;                      // [B*LQ, H]    512 KB
    float* ekT  = eq  + (size_t)B_ * LQ_ * H_;       // [B, H, LK]   1 MB
    float* attw = ekT + (size_t)B_ * H_ * LK_;       // [B*LQ, LK]   2 MB

    proj_kernel <<<NQBLK + NKBLK, 128, 0, stream>>>(queries, keys, Wq, Wk, eq, ekT);
    score_kernel<<<LQ_, 1024, 0, stream>>>(eq, ekT, wv, valid_lens, attw);
    pv_kernel   <<<B_ * LQ_ / 4, 1024, 0, stream>>>(attw, values, valid_lens, out);
}

// Round 8
// 29.980 us; speedup vs baseline: 1.4034x; 1.3743x over previous
//
#include <hip/hip_runtime.h>

// B=4, LQ=256, LK=512, DQ=DK=DV=256, H=128
#define B_   4
#define LQ_  256
#define LK_  512
#define DQK_ 256
#define DV_  256
#define H_   128

#define TANH_C 2.8853900817779268f   // 2*log2(e): tanh(x) = 1 - 2/(exp2(TANH_C*x)+1)
#define L2E    1.4426950408889634f
#define NQBLK (B_ * LQ_ / 4)         // 256 q-proj blocks (TILE=4)
#define NKBLK (B_ * LK_ / 4)         // 512 k-proj blocks

// ---------------------------------------------------------------------------
// proj_kernel (round-4 exact): fused q+k projection. TILE=4, 128 threads (t=h).
//   q blocks -> eq  [B*LQ, H]  = exp2(TANH_C * q@Wq)
//   k blocks -> ekT [B, H, LK] = exp2(TANH_C * k@Wk)   (transposed)
// ---------------------------------------------------------------------------
__global__ __launch_bounds__(128) void proj_kernel(const float* __restrict__ Q,
                                                   const float* __restrict__ K,
                                                   const float* __restrict__ Wq,
                                                   const float* __restrict__ Wk,
                                                   float* __restrict__ eq,
                                                   float* __restrict__ ekT) {
    const int blk = blockIdx.x;
    const bool isq = blk < NQBLK;
    const float* in = isq ? Q  : K;
    const float* W  = isq ? Wq : Wk;
    const int r0 = (isq ? blk : blk - NQBLK) * 4;
    const int t  = threadIdx.x;

    float acc0 = 0.f, acc1 = 0.f, acc2 = 0.f, acc3 = 0.f;
    const float4* in4 = reinterpret_cast<const float4*>(in + (size_t)r0 * DQK_);
    for (int d4 = 0; d4 < DQK_ / 4; ++d4) {
        float4 r0v = in4[0 * (DQK_ / 4) + d4];   // uniform -> s_load
        float4 r1v = in4[1 * (DQK_ / 4) + d4];
        float4 r2v = in4[2 * (DQK_ / 4) + d4];
        float4 r3v = in4[3 * (DQK_ / 4) + d4];
#pragma unroll
        for (int e = 0; e < 4; ++e) {
            float w = W[(size_t)(4 * d4 + e) * H_ + t];   // coalesced
            acc0 = fmaf(reinterpret_cast<const float*>(&r0v)[e], w, acc0);
            acc1 = fmaf(reinterpret_cast<const float*>(&r1v)[e], w, acc1);
            acc2 = fmaf(reinterpret_cast<const float*>(&r2v)[e], w, acc2);
            acc3 = fmaf(reinterpret_cast<const float*>(&r3v)[e], w, acc3);
        }
    }
    float e0 = __builtin_amdgcn_exp2f(acc0 * TANH_C);
    float e1 = __builtin_amdgcn_exp2f(acc1 * TANH_C);
    float e2 = __builtin_amdgcn_exp2f(acc2 * TANH_C);
    float e3 = __builtin_amdgcn_exp2f(acc3 * TANH_C);
    if (isq) {
        eq[(size_t)(r0 + 0) * H_ + t] = e0;
        eq[(size_t)(r0 + 1) * H_ + t] = e1;
        eq[(size_t)(r0 + 2) * H_ + t] = e2;
        eq[(size_t)(r0 + 3) * H_ + t] = e3;
    } else {
        const int b  = r0 >> 9;
        const int k0 = r0 & (LK_ - 1);
        float* o = ekT + ((size_t)(b * H_ + t)) * LK_ + k0;
        *reinterpret_cast<float4*>(o) = make_float4(e0, e1, e2, e3);
    }
}

// ---------------------------------------------------------------------------
// attn_kernel (round-4 structure, NO-MAX softmax): one block per (b, q-tile
// of 4), 1024 threads (16 waves).
//  Stage: Eq rows (4x128) + wm2 = -2*wv in LDS.
//  Phase B: thread (pair=t>>9, k=t&511): 2 qi chains sharing each ek load;
//           s = sum_h wm2[h] * rcp(fma(Eq[qi][h], Ek[h][k], 1))  (1 trans/elem;
//           +sum(wv) const cancels in softmax). |s| <= 2*sum|wv| ~ 18, so
//           exp needs NO max subtraction: store e = exp2(s*L2E) directly
//           (k >= valid -> e = 0, matching reference's underflowed exp).
//  Phase C: per-row sum reduction only -> inv_s.
//  Phase D: thread (kh=t>>8, v=t&255): 4 qi partials over its k-range
//           (clamped to valid), LDS reduce, scale by inv_s.
// ---------------------------------------------------------------------------
__global__ __launch_bounds__(1024) void attn_kernel(
    const float* __restrict__ eq,          // [B*LQ, H]
    const float* __restrict__ ekT,         // [B, H, LK]
    const float* __restrict__ wv,          // [H]
    const float* __restrict__ values,      // [B, LK, DV]
    const int*   __restrict__ valid_lens,  // [B]
    float* __restrict__ out) {             // [B*LQ, DV]
    __shared__ float eq_l[4][H_];          // 2 KB
    __shared__ float wm2[H_];              // 512 B
    __shared__ float sc[LK_][4];           // 8 KB (holds e values)
    __shared__ float part[4][4][DV_];      // 16 KB
    __shared__ float red[16];
    __shared__ float inv_s[4];

    const int blk = blockIdx.x;            // b*64 + qt
    const int b   = blk >> 6;
    const int qt  = blk & 63;
    const int t   = threadIdx.x;

    if (t < 512) {
        eq_l[t >> 7][t & 127] = eq[(size_t)(b * LQ_ + qt * 4 + (t >> 7)) * H_ + (t & 127)];
    } else if (t < 640) {
        wm2[t - 512] = -2.f * wv[t - 512];
    }
    __syncthreads();

    const int valid = valid_lens[b];

    // ---- Phase B: e-values for k = t&511, rows (2*pair, 2*pair+1) ----
    {
        const int k    = t & 511;
        const int pair = __builtin_amdgcn_readfirstlane(t >> 9);  // 0/1 wave-uniform
        float2 e2 = make_float2(0.f, 0.f);
        if (k < valid) {
            const float* ekp = ekT + (size_t)b * H_ * LK_ + k;
            const float4* w4  = reinterpret_cast<const float4*>(wm2);
            const float4* qa4 = reinterpret_cast<const float4*>(eq_l[2 * pair]);
            const float4* qb4 = reinterpret_cast<const float4*>(eq_l[2 * pair + 1]);
            float p0 = 0.f, p1 = 0.f;
#pragma unroll 4
            for (int h4 = 0; h4 < H_ / 4; ++h4) {
                float4 w  = w4[h4];
                float4 qa = qa4[h4];
                float4 qb = qb4[h4];
#pragma unroll
                for (int e = 0; e < 4; ++e) {
                    float ek = ekp[(size_t)(4 * h4 + e) * LK_];   // coalesced over k
                    float fa = fmaf(reinterpret_cast<const float*>(&qa)[e], ek, 1.f);
                    float fb = fmaf(reinterpret_cast<const float*>(&qb)[e], ek, 1.f);
                    float ww = reinterpret_cast<const float*>(&w)[e];
                    p0 = fmaf(ww, __builtin_amdgcn_rcpf(fa), p0);
                    p1 = fmaf(ww, __builtin_amdgcn_rcpf(fb), p1);
                }
            }
            e2 = make_float2(__builtin_amdgcn_exp2f(p0 * L2E),
                             __builtin_amdgcn_exp2f(p1 * L2E));
        }
        *reinterpret_cast<float2*>(&sc[k][2 * pair]) = e2;
    }
    __syncthreads();

    // ---- Phase C: per-row sum only (wave w -> row qi = w>>2) ----
    const int qi = t >> 8;                 // 0..3 wave-uniform
    const int kl = t & 255;
    {
        float ss = sc[kl][qi] + sc[kl + 256][qi];
#pragma unroll
        for (int off = 32; off; off >>= 1) ss += __shfl_down(ss, off, 64);
        if ((t & 63) == 0) red[t >> 6] = ss;
    }
    __syncthreads();
    if (t < 4) {
        inv_s[t] = 1.f / (red[4 * t] + red[4 * t + 1] + red[4 * t + 2] + red[4 * t + 3]);
    }
    __syncthreads();

    // ---- Phase D: out = attn @ values ----
    {
        const int kh = __builtin_amdgcn_readfirstlane(t >> 8);   // 0..3
        const int v  = t & 255;
        const int kstart = kh * 128;
        const int kend   = min(kstart + 128, valid);             // sc==0 beyond valid
        const float* vb = values + (size_t)b * LK_ * DV_ + v;
        float a0 = 0.f, a1 = 0.f, a2 = 0.f, a3 = 0.f;
#pragma unroll 4
        for (int k = kstart; k < kend; ++k) {
            float4 f  = *reinterpret_cast<const float4*>(&sc[k][0]);  // LDS broadcast
            float val = vb[(size_t)k * DV_];                          // coalesced over v
            a0 = fmaf(f.x, val, a0);
            a1 = fmaf(f.y, val, a1);
            a2 = fmaf(f.z, val, a2);
            a3 = fmaf(f.w, val, a3);
        }
        part[kh][0][v] = a0;
        part[kh][1][v] = a1;
        part[kh][2][v] = a2;
        part[kh][3][v] = a3;
    }
    __syncthreads();
    {
        const int v = t & 255;
        float r = (part[0][qi][v] + part[1][qi][v]) + (part[2][qi][v] + part[3][qi][v]);
        out[(size_t)(b * LQ_ + qt * 4 + qi) * DV_ + v] = r * inv_s[qi];
    }
}

extern "C" void kernel_launch(void* const* d_in, const int* in_sizes, int n_in,
                              void* d_out, int out_size, void* d_ws, size_t ws_size,
                              hipStream_t stream) {
    const float* queries    = (const float*)d_in[0];  // [B, LQ, DQ]
    const float* keys       = (const float*)d_in[1];  // [B, LK, DK]
    const float* values     = (const float*)d_in[2];  // [B, LK, DV]
    const float* Wq         = (const float*)d_in[3];  // [DQ, H]
    const float* Wk         = (const float*)d_in[4];  // [DK, H]
    const float* wv         = (const float*)d_in[5];  // [H]
    const int*   valid_lens = (const int*)d_in[6];    // [B]
    float* out = (float*)d_out;

    float* eq  = (float*)d_ws;                   // [B*LQ, H]   512 KB
    float* ekT = eq + (size_t)B_ * LQ_ * H_;     // [B, H, LK]  1 MB

    proj_kernel<<<NQBLK + NKBLK, 128, 0, stream>>>(queries, keys, Wq, Wk, eq, ekT);
    attn_kernel<<<B_ * LQ_ / 4, 1024, 0, stream>>>(eq, ekT, wv, values, valid_lens, out);
}

// Round 9
// 28.974 us; speedup vs baseline: 1.4521x; 1.0347x over previous
//
#include <hip/hip_runtime.h>

// B=4, LQ=256, LK=512, DQ=DK=DV=256, H=128
#define B_   4
#define LQ_  256
#define LK_  512
#define DQK_ 256
#define DV_  256
#define H_   128

#define TANH_C 2.8853900817779268f   // 2*log2(e): tanh(x) = 1 - 2/(exp2(TANH_C*x)+1)
#define L2E    1.4426950408889634f
#define NQBLK (B_ * LQ_ / 4)         // 256 q-proj blocks (TILE=4)
#define NKBLK (B_ * LK_ / 4)         // 512 k-proj blocks

// ---------------------------------------------------------------------------
// proj_kernel (round-4 exact, proven): fused q+k projection. TILE=4, 128 thr.
//   q blocks -> eq  [B*LQ, H]  = exp2(TANH_C * q@Wq)
//   k blocks -> ekT [B, H, LK] = exp2(TANH_C * k@Wk)   (transposed)
// ---------------------------------------------------------------------------
__global__ __launch_bounds__(128) void proj_kernel(const float* __restrict__ Q,
                                                   const float* __restrict__ K,
                                                   const float* __restrict__ Wq,
                                                   const float* __restrict__ Wk,
                                                   float* __restrict__ eq,
                                                   float* __restrict__ ekT) {
    const int blk = blockIdx.x;
    const bool isq = blk < NQBLK;
    const float* in = isq ? Q  : K;
    const float* W  = isq ? Wq : Wk;
    const int r0 = (isq ? blk : blk - NQBLK) * 4;
    const int t  = threadIdx.x;

    float acc0 = 0.f, acc1 = 0.f, acc2 = 0.f, acc3 = 0.f;
    const float4* in4 = reinterpret_cast<const float4*>(in + (size_t)r0 * DQK_);
    for (int d4 = 0; d4 < DQK_ / 4; ++d4) {
        float4 r0v = in4[0 * (DQK_ / 4) + d4];   // uniform -> s_load
        float4 r1v = in4[1 * (DQK_ / 4) + d4];
        float4 r2v = in4[2 * (DQK_ / 4) + d4];
        float4 r3v = in4[3 * (DQK_ / 4) + d4];
#pragma unroll
        for (int e = 0; e < 4; ++e) {
            float w = W[(size_t)(4 * d4 + e) * H_ + t];   // coalesced
            acc0 = fmaf(reinterpret_cast<const float*>(&r0v)[e], w, acc0);
            acc1 = fmaf(reinterpret_cast<const float*>(&r1v)[e], w, acc1);
            acc2 = fmaf(reinterpret_cast<const float*>(&r2v)[e], w, acc2);
            acc3 = fmaf(reinterpret_cast<const float*>(&r3v)[e], w, acc3);
        }
    }
    float e0 = __builtin_amdgcn_exp2f(acc0 * TANH_C);
    float e1 = __builtin_amdgcn_exp2f(acc1 * TANH_C);
    float e2 = __builtin_amdgcn_exp2f(acc2 * TANH_C);
    float e3 = __builtin_amdgcn_exp2f(acc3 * TANH_C);
    if (isq) {
        eq[(size_t)(r0 + 0) * H_ + t] = e0;
        eq[(size_t)(r0 + 1) * H_ + t] = e1;
        eq[(size_t)(r0 + 2) * H_ + t] = e2;
        eq[(size_t)(r0 + 3) * H_ + t] = e3;
    } else {
        const int b  = r0 >> 9;
        const int k0 = r0 & (LK_ - 1);
        float* o = ekT + ((size_t)(b * H_ + t)) * LK_ + k0;
        *reinterpret_cast<float4*>(o) = make_float4(e0, e1, e2, e3);
    }
}

// ---------------------------------------------------------------------------
// attn_kernel: one block per (b, q-tile of 4), 1024 threads (16 waves).
//  Phase B (vectorized+dedup): thread (hs = t>>7 in 0..7, quad = t&127) owns
//    k = 4*quad..4*quad+3 over h in 16*hs..16*hs+15 for ALL 4 q-rows:
//    ek loaded ONCE per block via float4 (1 KB contiguous per wave-inst);
//    16 accumulators/thread; partials -> LDS partB[8][128][20].
//  Score stage: sum 8 h-slices, e = (k<valid) ? exp2(s*L2E) : 0 -> sc[k][r]
//    (|s| <= 2*sum|wv| ~ 18 so no max subtraction needed).
//  Phase C: per-row sum reduction -> inv_s (R8 code).
//  Phase D (vectorized): wave w = t>>6 owns k-slice 32w..32w+31; lane owns
//    v = 4*(t&63)..+3; float4 values loads; 16 fma/k; partials in LDS
//    partD[16][4][256] (aliases partB scratch), reduced at the out stage.
// ---------------------------------------------------------------------------
__global__ __launch_bounds__(1024) void attn_kernel(
    const float* __restrict__ eq,          // [B*LQ, H]
    const float* __restrict__ ekT,         // [B, H, LK]
    const float* __restrict__ wv,          // [H]
    const float* __restrict__ values,      // [B, LK, DV]
    const int*   __restrict__ valid_lens,  // [B]
    float* __restrict__ out) {             // [B*LQ, DV]
    __shared__ float eq_l[4][H_];          // 2 KB
    __shared__ float wm2[H_];              // 512 B
    __shared__ float sc[LK_][4];           // 8 KB (e-values, [k][row])
    __shared__ float scratch[8 * 128 * 20];// 80 KB: partB then partD
    __shared__ float red[16];
    __shared__ float inv_s[4];

    float (*partB)[128][20] = reinterpret_cast<float (*)[128][20]>(scratch);
    float (*partD)[4][DV_]  = reinterpret_cast<float (*)[4][DV_]>(scratch);

    const int blk = blockIdx.x;            // b*64 + qt
    const int b   = blk >> 6;
    const int qt  = blk & 63;
    const int t   = threadIdx.x;

    if (t < 512) {
        eq_l[t >> 7][t & 127] = eq[(size_t)(b * LQ_ + qt * 4 + (t >> 7)) * H_ + (t & 127)];
    } else if (t < 640) {
        wm2[t - 512] = -2.f * wv[t - 512];
    }
    __syncthreads();

    const int valid = valid_lens[b];

    // ---- Phase B: register-blocked partial scores ----
    {
        const int quad = t & 127;          // k-quad: k = 4*quad + e
        const int hs   = t >> 7;           // h-slice: h = 16*hs + hh
        const int k0   = 4 * quad;
        float acc[16];
#pragma unroll
        for (int i = 0; i < 16; ++i) acc[i] = 0.f;

        if (k0 < valid) {
            const float* ekb = ekT + (size_t)b * H_ * LK_ + k0;
#pragma unroll 2
            for (int hh = 0; hh < 16; ++hh) {
                const int h = 16 * hs + hh;
                float4 ek = *reinterpret_cast<const float4*>(ekb + (size_t)h * LK_);
                float w = wm2[h];          // LDS broadcast
#pragma unroll
                for (int r = 0; r < 4; ++r) {
                    float qv = eq_l[r][h]; // LDS broadcast
                    acc[4 * r + 0] = fmaf(w, __builtin_amdgcn_rcpf(fmaf(qv, ek.x, 1.f)), acc[4 * r + 0]);
                    acc[4 * r + 1] = fmaf(w, __builtin_amdgcn_rcpf(fmaf(qv, ek.y, 1.f)), acc[4 * r + 1]);
                    acc[4 * r + 2] = fmaf(w, __builtin_amdgcn_rcpf(fmaf(qv, ek.z, 1.f)), acc[4 * r + 2]);
                    acc[4 * r + 3] = fmaf(w, __builtin_amdgcn_rcpf(fmaf(qv, ek.w, 1.f)), acc[4 * r + 3]);
                }
            }
        }
        float* pb = &partB[hs][quad][0];
#pragma unroll
        for (int i = 0; i < 4; ++i)
            *reinterpret_cast<float4*>(pb + 4 * i) = *reinterpret_cast<float4*>(&acc[4 * i]);
    }
    __syncthreads();

    // ---- Score stage: reduce 8 h-slices, exp2, mask -> sc[k][r] ----
#pragma unroll
    for (int j = 0; j < 2; ++j) {
        const int o    = t + 1024 * j;     // 0..2047
        const int quad = o >> 4;
        const int idx  = o & 15;           // r*4 + e
        const int k    = 4 * quad + (idx & 3);
        float s = 0.f;
#pragma unroll
        for (int hs = 0; hs < 8; ++hs) s += partB[hs][quad][idx];
        sc[k][idx >> 2] = (k < valid) ? __builtin_amdgcn_exp2f(s * L2E) : 0.f;
    }
    __syncthreads();

    // ---- Phase C: per-row sum only (wave w -> row qi = w>>2) ----
    const int qi = t >> 8;                 // 0..3 wave-uniform
    const int kl = t & 255;
    {
        float ss = sc[kl][qi] + sc[kl + 256][qi];
#pragma unroll
        for (int off = 32; off; off >>= 1) ss += __shfl_down(ss, off, 64);
        if ((t & 63) == 0) red[t >> 6] = ss;
    }
    __syncthreads();
    if (t < 4) {
        inv_s[t] = 1.f / (red[4 * t] + red[4 * t + 1] + red[4 * t + 2] + red[4 * t + 3]);
    }
    __syncthreads();                        // also fences partB before partD reuse

    // ---- Phase D: out = attn @ values (float4 values, wave-per-k-slice) ----
    {
        const int w  = __builtin_amdgcn_readfirstlane(t >> 6);  // wave 0..15
        const int v  = 4 * (t & 63);
        const int kstart = 32 * w;
        const int kend   = min(kstart + 32, valid);
        const float* vb = values + (size_t)b * LK_ * DV_ + v;
        float4 a0 = make_float4(0.f, 0.f, 0.f, 0.f);
        float4 a1 = a0, a2 = a0, a3 = a0;
#pragma unroll 2
        for (int k = kstart; k < kend; ++k) {
            float4 sv = *reinterpret_cast<const float4*>(&sc[k][0]);     // broadcast
            float4 vv = *reinterpret_cast<const float4*>(vb + (size_t)k * DV_); // coalesced
            a0.x = fmaf(sv.x, vv.x, a0.x); a0.y = fmaf(sv.x, vv.y, a0.y);
            a0.z = fmaf(sv.x, vv.z, a0.z); a0.w = fmaf(sv.x, vv.w, a0.w);
            a1.x = fmaf(sv.y, vv.x, a1.x); a1.y = fmaf(sv.y, vv.y, a1.y);
            a1.z = fmaf(sv.y, vv.z, a1.z); a1.w = fmaf(sv.y, vv.w, a1.w);
            a2.x = fmaf(sv.z, vv.x, a2.x); a2.y = fmaf(sv.z, vv.y, a2.y);
            a2.z = fmaf(sv.z, vv.z, a2.z); a2.w = fmaf(sv.z, vv.w, a2.w);
            a3.x = fmaf(sv.w, vv.x, a3.x); a3.y = fmaf(sv.w, vv.y, a3.y);
            a3.z = fmaf(sv.w, vv.z, a3.z); a3.w = fmaf(sv.w, vv.w, a3.w);
        }
        *reinterpret_cast<float4*>(&partD[w][0][v]) = a0;
        *reinterpret_cast<float4*>(&partD[w][1][v]) = a1;
        *reinterpret_cast<float4*>(&partD[w][2][v]) = a2;
        *reinterpret_cast<float4*>(&partD[w][3][v]) = a3;
    }
    __syncthreads();
    {
        const int r = t >> 8;
        const int v = t & 255;
        float s = 0.f;
#pragma unroll
        for (int w = 0; w < 16; ++w) s += partD[w][r][v];
        out[(size_t)(b * LQ_ + qt * 4 + r) * DV_ + v] = s * inv_s[r];
    }
}

extern "C" void kernel_launch(void* const* d_in, const int* in_sizes, int n_in,
                              void* d_out, int out_size, void* d_ws, size_t ws_size,
                              hipStream_t stream) {
    const float* queries    = (const float*)d_in[0];  // [B, LQ, DQ]
    const float* keys       = (const float*)d_in[1];  // [B, LK, DK]
    const float* values     = (const float*)d_in[2];  // [B, LK, DV]
    const float* Wq         = (const float*)d_in[3];  // [DQ, H]
    const float* Wk         = (const float*)d_in[4];  // [DK, H]
    const float* wv         = (const float*)d_in[5];  // [H]
    const int*   valid_lens = (const int*)d_in[6];    // [B]
    float* out = (float*)d_out;

    float* eq  = (float*)d_ws;                   // [B*LQ, H]   512 KB
    float* ekT = eq + (size_t)B_ * LQ_ * H_;     // [B, H, LK]  1 MB

    proj_kernel<<<NQBLK + NKBLK, 128, 0, stream>>>(queries, keys, Wq, Wk, eq, ekT);
    attn_kernel<<<B_ * LQ_ / 4, 1024, 0, stream>>>(eq, ekT, wv, values, valid_lens, out);
}